// Round 2
// 6395.804 us; speedup vs baseline: 1.8652x; 1.8652x over previous
//
#include <hip/hip_runtime.h>
#include <cstddef>
#include <math.h>

// Problem: B=64, S=1024, F=128, H=512, V=64, T=64. f32 in/out.
// R8 = R7 (batch-partitioned groups) + correctness fix:
//  - R7's NaN: STAGE_H unpacked ld16f asm results with register-only VALU ops;
//    hipcc hoists those above the inline-asm s_waitcnt vmcnt(0) (guide rule
//    #18, m214 r263/r282) -> reads VGPRs before the load returns. Fix: tie
//    values through volatile asm + sched_barrier(0) after VMWAIT.
//  - aligned(16) on LDS arrays touched by b128 ops (f16/float arrays only get
//    2/4B natural alignment).
// Design recap:
//  - 4 groups x 16 batches; per group 32 WGs slice H (16 h-dims/WG, 1 gate/wave).
//    128 WGs total, no cross-group sync. W_hh/W_ih hi/lo Ootomo f16 fragments
//    register-resident per wave.
//  - Per step per WG: x-part MFMA (h-independent) -> flag wait -> ONE-SHOT h
//    stage to LDS (8 far ld16f/thread, 1 VMWAIT, 1 barrier; h packed u32 =
//    hi|lo<<16) -> 64 h-MFMAs -> gate LDS exchange -> cell (1 h/thread) ->
//    1 packed far store -> VMWAIT -> flag.
//  - LDS h tiles [16][512] f16 unpadded + XOR swizzle (byte ^= (row&7)<<4) on
//    write AND read: conflict-free b128.
//  - Exchange primitives R4-proven: relaxed agent atomic stores + VMWAIT +
//    flag; loads = global_load_dwordx4 sc0 sc1 (batched far loads).
#define NGROUP 4
#define WPG    32
#define NWG    128
#define BPG    16
#define BB  64
#define HH  512
#define TT  64
#define VV  64
#define FF  128
#define SS  1024

typedef _Float16 f16;
typedef _Float16 f16x8 __attribute__((ext_vector_type(8)));
typedef float    f32x4 __attribute__((ext_vector_type(4)));
typedef unsigned int u32;
typedef u32 u32x4 __attribute__((ext_vector_type(4)));
typedef unsigned long long u64;

#define C1 4.8828125e-4f          // 2^-11
#define C2 2.384185791015625e-7f  // 2^-22

__device__ __forceinline__ void split8(const float* __restrict__ p, f16x8& hi, f16x8& lo) {
  f32x4 u = *(const f32x4*)p;
  f32x4 v = *(const f32x4*)(p + 4);
#pragma unroll
  for (int j = 0; j < 4; ++j) {
    f16 a = (f16)u[j]; hi[j]   = a; lo[j]   = (f16)((u[j] - (float)a) * 2048.0f);
    f16 b = (f16)v[j]; hi[4+j] = b; lo[4+j] = (f16)((v[j] - (float)b) * 2048.0f);
  }
}
__device__ __forceinline__ float sigmf_(float x) { return 1.0f / (1.0f + expf(-x)); }

// far (coherence-point) accessors — R4-proven pattern
__device__ __forceinline__ f32x4 ld16f(const void* p) {
  f32x4 r;
  asm volatile("global_load_dwordx4 %0, %1, off sc0 sc1" : "=v"(r) : "v"(p) : "memory");
  return r;
}
__device__ __forceinline__ void st4f(u32* p, u32 v) {
  __hip_atomic_store(p, v, __ATOMIC_RELAXED, __HIP_MEMORY_SCOPE_AGENT);
}
__device__ __forceinline__ void st4ff(float* p, float v) {
  __hip_atomic_store(p, v, __ATOMIC_RELAXED, __HIP_MEMORY_SCOPE_AGENT);
}
__device__ __forceinline__ u32 ld4f(const u32* p) {
  return __hip_atomic_load(p, __ATOMIC_RELAXED, __HIP_MEMORY_SCOPE_AGENT);
}
#define VMWAIT asm volatile("s_waitcnt vmcnt(0)" ::: "memory")

// barrier: poll this group's 32 per-WG flags with one 64-lane gather
__device__ __forceinline__ void wait_flags(const u32* flags, u32 target, int lane) {
  const u32* a = flags + (size_t)(lane & 31) * 32;   // 128B stride
  while (!__all(ld4f(a) >= target))
    __builtin_amdgcn_s_sleep(1);
}

#define MFMA(d, a, b) d = __builtin_amdgcn_mfma_f32_16x16x32_f16(a, b, d, 0, 0, 0)

// one-shot h stage: group h tile [16][512] packed u32 -> LDS hi/lo f16, swizzled.
// CRITICAL (rule #18): after VMWAIT, tie sv through volatile asm + sched_barrier
// so the register-only unpack cannot be scheduled before the vmcnt wait.
#define STAGE_H(src_)                                                         \
  { const u32* src = (src_) + (size_t)(tid >> 4) * HH + (size_t)(tid & 15) * 32; \
    f32x4 sv[8];                                                              \
    _Pragma("unroll") for (int u2 = 0; u2 < 8; ++u2)                          \
      sv[u2] = ld16f(src + u2 * 4);                                           \
    VMWAIT;                                                                   \
    _Pragma("unroll") for (int u2 = 0; u2 < 8; ++u2)                          \
      asm volatile("" : "+v"(sv[u2]));                                        \
    __builtin_amdgcn_sched_barrier(0);                                        \
    const int srb = tid >> 4;                                                 \
    const size_t sbase = (size_t)srb * 1024 + (size_t)(tid & 15) * 64;        \
    const size_t swz = (size_t)((srb & 7) << 4);                              \
    _Pragma("unroll") for (int c2 = 0; c2 < 4; ++c2) {                        \
      union { f32x4 f; u32 u[4]; } Ua, Ub;                                    \
      Ua.f = sv[2*c2]; Ub.f = sv[2*c2 + 1];                                   \
      u32 h0_=(Ua.u[0]&0xffffu)|(Ua.u[1]<<16), h1_=(Ua.u[2]&0xffffu)|(Ua.u[3]<<16); \
      u32 h2_=(Ub.u[0]&0xffffu)|(Ub.u[1]<<16), h3_=(Ub.u[2]&0xffffu)|(Ub.u[3]<<16); \
      u32 l0_=(Ua.u[0]>>16)|(Ua.u[1]&0xffff0000u), l1_=(Ua.u[2]>>16)|(Ua.u[3]&0xffff0000u); \
      u32 l2_=(Ub.u[0]>>16)|(Ub.u[1]&0xffff0000u), l3_=(Ub.u[2]>>16)|(Ub.u[3]&0xffff0000u); \
      size_t off = (sbase + (size_t)c2 * 16) ^ swz;                           \
      *(u32x4*)((char*)sh_hi + off) = (u32x4){h0_, h1_, h2_, h3_};            \
      *(u32x4*)((char*)sh_lo + off) = (u32x4){l0_, l1_, l2_, l3_};            \
    } }                                                                       \
  __syncthreads();

// A-fragment read (row = batch mn, k-slice s), same swizzle as write side
#define LDA(s, ah, al)                                                        \
  { size_t o_ = ((size_t)mn * 1024 + (size_t)(s) * 64 + (size_t)(q8 * 2))     \
                ^ (size_t)((mn & 7) << 4);                                    \
    ah = *(const f16x8*)((const char*)sh_hi + o_);                            \
    al = *(const f16x8*)((const char*)sh_lo + o_); }

#define HPART()                                                               \
  _Pragma("unroll") for (int s = 0; s < 16; ++s) {                            \
    f16x8 ah, al; LDA(s, ah, al);                                             \
    MFMA(acc0, ah, whh_h[s]);                                                 \
    MFMA(acc1, al, whh_h[s]);                                                 \
    MFMA(acc1, ah, whh_l[s]);                                                 \
    MFMA(acc2, al, whh_l[s]);                                                 \
  }

// C/D layout: col = lane&15 = h-dim, row = (lane>>4)*4 + r = batch
#define GWRITE()                                                              \
  _Pragma("unroll") for (int r = 0; r < 4; ++r)                               \
    gate_buf[w][q * 4 + r][mn] = acc0[r] + C1 * acc1[r] + C2 * acc2[r];

__global__ void __launch_bounds__(256, 1) lstm_seq2seq(
    const float* __restrict__ sig,   // [B,S,F]
    const int*   __restrict__ tgt,   // [B,T]
    const float* __restrict__ eWih,  // [2048,128]
    const float* __restrict__ eWhh,  // [2048,512]
    const float* __restrict__ eBih,  // [2048]
    const float* __restrict__ eBhh,  // [2048]
    const float* __restrict__ dWih,  // [2048,64]
    const float* __restrict__ dWhh,  // [2048,512]
    const float* __restrict__ dBih,  // [2048]
    const float* __restrict__ dBhh,  // [2048]
    const float* __restrict__ oW,    // [64,512]
    const float* __restrict__ oB,    // [64]
    float*       __restrict__ out,   // [B,T,V]
    unsigned char* __restrict__ ws)
{
  // ws layout (bytes): [0,16384) flags 4 groups x 32 x 128B;
  // [16384,16640) idxbuf u32[64]; [20480,282624) h16 4 groups x 2 buf x 32KB;
  // [282624,413696) hf32 4 groups x 32KB. Zeroed region = [0,282624).
  const int wg = blockIdx.x;
  const int g  = wg >> 5;            // batch group
  const int p  = wg & 31;            // h-dim slice [p*16, p*16+16) per gate
  const int gb = g * BPG;            // global batch base
  u32* fl     = (u32*)ws + (size_t)g * 1024;
  u32* idxbuf = (u32*)(ws + 16384);
  u32* h16[2] = { (u32*)(ws + 20480) + (size_t)(g*2 + 0) * 8192,
                  (u32*)(ws + 20480) + (size_t)(g*2 + 1) * 8192 };
  float* hfg  = (float*)(ws + 282624) + (size_t)g * 8192;

  const int tid  = threadIdx.x;
  const int w    = tid >> 6;         // wave = gate (i,f,g,o)
  const int lane = tid & 63;
  const int q    = lane >> 4;
  const int mn   = lane & 15;
  const int q8   = q * 8;
  const int row  = w * HH + p * 16 + mn;  // weight row for this lane's B-frag
  const int cb   = tid >> 4;         // cell: local batch 0..15
  const int ck   = tid & 15;         // cell: dim within slice
  const int crow = p * 16 + ck;      // cell: h-dim

  __shared__ __attribute__((aligned(16))) f16 sh_hi[16 * 512]; // 16KB swizzled
  __shared__ __attribute__((aligned(16))) f16 sh_lo[16 * 512]; // single-buffered
  __shared__ float gate_buf[4][16][17];
  __shared__ float bias_buf[4][16];
  __shared__ __attribute__((aligned(16))) float hrow[512];
  __shared__ double psum[64];

  // ---- weights: W_hh and W_ih hi/lo fragments in registers ----
  f16x8 whh_h[16], whh_l[16], wih_h[4], wih_l[4];
#pragma unroll
  for (int s = 0; s < 16; ++s)
    split8(eWhh + (size_t)row * HH + s * 32 + q8, whh_h[s], whh_l[s]);
#pragma unroll
  for (int s = 0; s < 4; ++s)
    split8(eWih + (size_t)row * FF + s * 32 + q8, wih_h[s], wih_l[s]);
  if (tid < 64) {
    int g4 = tid >> 4, kl = tid & 15;
    int r = g4 * HH + p * 16 + kl;
    bias_buf[g4][kl] = eBih[r] + eBhh[r];
  }
  if (p == 0 && tid < BPG)
    st4f(idxbuf + gb + tid, (u32)tgt[(size_t)(gb + tid) * TT]);  // target[:,0]
  __syncthreads();

  float c_reg = 0.f;
  int cur = 0;                       // h dbuf (zeroed by memset = h0)
  const f32x4 zero4 = {0.f, 0.f, 0.f, 0.f};

  // ================= encoder: 1024 steps =================
  for (int t = 0; t < SS; ++t) {
    f32x4 acc0 = zero4, acc1 = zero4, acc2 = zero4;
    // x-part: h-independent, overlaps other WGs finishing step t-1
    const float* sb = sig + (size_t)(gb + mn) * (SS * FF) + (size_t)t * FF;
#pragma unroll
    for (int s = 0; s < 4; ++s) {
      f16x8 ah, al;
      split8(sb + s * 32 + q8, ah, al);
      MFMA(acc0, ah, wih_h[s]);
      MFMA(acc1, al, wih_h[s]);
      MFMA(acc1, ah, wih_l[s]);
      MFMA(acc2, al, wih_l[s]);
    }
    wait_flags(fl, (u32)t, lane);
    STAGE_H(h16[cur])
    HPART()
    GWRITE()
    __syncthreads();
    // LSTM cell: 1 h-value per thread (f32, precise libm)
    {
      float gi = gate_buf[0][cb][ck] + bias_buf[0][ck];
      float gf = gate_buf[1][cb][ck] + bias_buf[1][ck];
      float gg = gate_buf[2][cb][ck] + bias_buf[2][ck];
      float go = gate_buf[3][cb][ck] + bias_buf[3][ck];
      float c  = sigmf_(gf) * c_reg + sigmf_(gi) * tanhf(gg);
      float h  = sigmf_(go) * tanhf(c);
      c_reg = c;
      f16 hh = (f16)h;
      f16 hl = (f16)((h - (float)hh) * 2048.0f);
      union { f16 h2[2]; u32 u; } pk;
      pk.h2[0] = hh; pk.h2[1] = hl;
      st4f(h16[cur ^ 1] + (size_t)cb * HH + crow, pk.u);
    }
    VMWAIT;             // h store acked at coherence point
    __syncthreads();
    if (tid == 0) st4f(fl + p * 32, (u32)(t + 1));
    cur ^= 1;
  }

  // ================= decoder setup =================
#pragma unroll
  for (int s = 0; s < 16; ++s)
    split8(dWhh + (size_t)row * HH + s * 32 + q8, whh_h[s], whh_l[s]);
  __syncthreads();
  if (tid < 64) {
    int g4 = tid >> 4, kl = tid & 15;
    int r = g4 * HH + p * 16 + kl;
    bias_buf[g4][kl] = dBih[r] + dBhh[r];
  }
  __syncthreads();

  // ================= decoder: 64 steps =================
  for (int t = 0; t < TT; ++t) {
    // ---- phase A: cell. x = one_hot(idx) -> column gather at cell stage ----
    wait_flags(fl, (u32)(SS + 2 * t), lane);
    f32x4 acc0 = zero4, acc1 = zero4, acc2 = zero4;
    STAGE_H(h16[cur])
    HPART()
    GWRITE()
    __syncthreads();
    {
      int ib = (int)ld4f(idxbuf + gb + cb);
      float gi = gate_buf[0][cb][ck] + bias_buf[0][ck] + dWih[(size_t)(0*HH + crow) * VV + ib];
      float gf = gate_buf[1][cb][ck] + bias_buf[1][ck] + dWih[(size_t)(1*HH + crow) * VV + ib];
      float gg = gate_buf[2][cb][ck] + bias_buf[2][ck] + dWih[(size_t)(2*HH + crow) * VV + ib];
      float go = gate_buf[3][cb][ck] + bias_buf[3][ck] + dWih[(size_t)(3*HH + crow) * VV + ib];
      float c  = sigmf_(gf) * c_reg + sigmf_(gi) * tanhf(gg);
      float h  = sigmf_(go) * tanhf(c);
      c_reg = c;
      f16 hh = (f16)h;
      f16 hl = (f16)((h - (float)hh) * 2048.0f);
      union { f16 h2[2]; u32 u; } pk;
      pk.h2[0] = hh; pk.h2[1] = hl;
      st4f(h16[cur ^ 1] + (size_t)cb * HH + crow, pk.u);
      st4ff(hfg + (size_t)cb * HH + crow, h);
    }
    VMWAIT;
    __syncthreads();
    if (tid == 0) st4f(fl + p * 32, (u32)(SS + 2 * t + 1));
    int nxt = cur ^ 1;

    // ---- phase B: f64 logits + log_softmax + argmax (WG p<16 = batch p) ----
    wait_flags(fl, (u32)(SS + 2 * t + 1), lane);
    if (p < BPG) {
      if (tid < 128) {
        f32x4 hv = ld16f(hfg + (size_t)p * HH + tid * 4);
        VMWAIT;
        *(f32x4*)&hrow[tid * 4] = hv;
      }
      __syncthreads();
      double acc = 0.0;
      if (w < 2) {                   // waves 0,1 split K=512 in halves
        const float* wr = oW + (size_t)lane * HH + w * 256;
        const float* hr = hrow + w * 256;
#pragma unroll 4
        for (int kc = 0; kc < 64; ++kc) {
          f32x4 hv = *(const f32x4*)(hr + kc * 4);
          f32x4 wv = *(const f32x4*)(wr + kc * 4);
          acc += (double)hv[0]*(double)wv[0] + (double)hv[1]*(double)wv[1]
               + (double)hv[2]*(double)wv[2] + (double)hv[3]*(double)wv[3];
        }
        if (w == 1) psum[lane] = acc;
      }
      __syncthreads();
      if (w == 0) {
        double l = acc + psum[lane] + (double)oB[lane];
        double mx = l; int ai = lane;
#pragma unroll
        for (int o = 32; o > 0; o >>= 1) {
          double om = __shfl_xor(mx, o, 64);
          int    oi = __shfl_xor(ai, o, 64);
          if (om > mx || (om == mx && oi < ai)) { mx = om; ai = oi; }
        }
        double se = exp(l - mx);
#pragma unroll
        for (int o = 32; o > 0; o >>= 1) se += __shfl_xor(se, o, 64);
        double lse = mx + log(se);
        out[((size_t)(gb + p) * TT + t) * VV + lane] = (float)(l - lse);
        if (lane == 0) st4f(idxbuf + gb + p, (u32)ai);
      }
    }
    VMWAIT;
    __syncthreads();
    if (tid == 0) st4f(fl + p * 32, (u32)(SS + 2 * t + 2));
    cur = nxt;
  }
}

extern "C" void kernel_launch(void* const* d_in, const int* in_sizes, int n_in,
                              void* d_out, int out_size, void* d_ws, size_t ws_size,
                              hipStream_t stream) {
  (void)in_sizes; (void)n_in; (void)out_size; (void)ws_size;
  // zero: flags + idxbuf + h16 dbufs (ws re-poisoned 0xAA before every timed
  // launch -> must zero every call). hf32 fully written before read.
  hipMemsetAsync(d_ws, 0, 282624, stream);
  lstm_seq2seq<<<dim3(NWG), dim3(256), 0, stream>>>(
      (const float*)d_in[0],  (const int*)d_in[1],
      (const float*)d_in[2],  (const float*)d_in[3],
      (const float*)d_in[4],  (const float*)d_in[5],
      (const float*)d_in[6],  (const float*)d_in[7],
      (const float*)d_in[8],  (const float*)d_in[9],
      (const float*)d_in[10], (const float*)d_in[11],
      (float*)d_out, (unsigned char*)d_ws);
}